// Round 1
// baseline (449.398 us; speedup 1.0000x reference)
//
#include <hip/hip_runtime.h>
#include <hip/hip_bf16.h>

typedef __attribute__((ext_vector_type(8))) short bf16x8;
typedef __attribute__((ext_vector_type(4))) float f32x4;
typedef unsigned int u32;
typedef unsigned short u16;
typedef unsigned long long u64;

// B=4, S=2048, D=1024, H=16, DH=64

__device__ __forceinline__ void gload_lds16(const void* g, void* l) {
    __builtin_amdgcn_global_load_lds(
        (const __attribute__((address_space(1))) void*)g,
        (__attribute__((address_space(3))) void*)l, 16, 0, 0);
}

__device__ __forceinline__ u16 f2bf(float f) {
    u32 u = __builtin_bit_cast(u32, f);
    u32 r = u + 0x7fffu + ((u >> 16) & 1u);
    return (u16)(r >> 16);
}

// ---------------- f32 -> bf16 convert (vectorized, grid-stride) ----------------
__global__ void k_cvt(const float* __restrict__ in, u16* __restrict__ out, int n) {
    int i = (blockIdx.x * blockDim.x + threadIdx.x) * 4;
    int stride = gridDim.x * blockDim.x * 4;
    for (; i < n; i += stride) {
        float4 v = *(const float4*)(in + i);
        ushort4 o = make_ushort4(f2bf(v.x), f2bf(v.y), f2bf(v.z), f2bf(v.w));
        *(ushort4*)(out + i) = o;
    }
}

// ---------------- pack [H][D][DH] f32 -> bf16 Bt [H*DH][D] ----------------
__global__ void k_pack_w(const float* __restrict__ W, u16* __restrict__ Wt) {
    int i = blockIdx.x * 256 + threadIdx.x;   // over 16*1024*64 = 1048576
    int h = i >> 16;
    int r = i & 65535;
    int k = r >> 6, e = r & 63;
    Wt[(size_t)(h * 64 + e) * 1024 + k] = f2bf(W[i]);
}

// ---------------- pack Wo [1024][64] -> bf16 [64][1024] ----------------
__global__ void k_pack_wo(const float* __restrict__ W, u16* __restrict__ Wt) {
    int i = blockIdx.x * 256 + threadIdx.x;   // over 65536
    int k = i >> 6, e = i & 63;
    Wt[(size_t)e * 1024 + k] = f2bf(W[i]);
}

// ---------------- pack mask int32 -> bitmask ----------------
__global__ void k_pack_mask(const int* __restrict__ mask, u32* __restrict__ bits) {
    size_t i = (size_t)blockIdx.x * 256 + threadIdx.x;  // over B*S*S = 16777216
    int m = mask[i];
    u64 bal = __ballot(m != 0);
    if ((threadIdx.x & 63) == 0) *(u64*)(bits + (i >> 5)) = bal;
}

// ---------------- projection GEMM: C[8192,1024] = A[8192,1024] @ Bt^T + bias ----------------
// mode 0: out[((b*16+h)*2048 + s)*64 + e]   (q, k)
// mode 1: out[((b*16+h)*64 + e)*2048 + s]   (v transposed)
__global__ __launch_bounds__(256) void k_proj(
    const u16* __restrict__ A, const u16* __restrict__ Bt,
    const float* __restrict__ bias, u16* __restrict__ out, int mode)
{
    __shared__ char smem[16384];
    const int tid = threadIdx.x, lane = tid & 63, w = tid >> 6;
    const int wr = w >> 1, wc = w & 1;
    const int fr = lane & 15, fq = lane >> 4;
    const int m0 = blockIdx.y * 128, n0 = blockIdx.x * 128;

    const int arow = w * 32 + (lane >> 2);   // +t*16
    const int aseg = (lane & 3) * 8;

    f32x4 acc[4][4] = {};

    for (int kt = 0; kt < 1024; kt += 32) {
#pragma unroll
        for (int t = 0; t < 2; ++t) {
            gload_lds16(A + (size_t)(m0 + arow + t * 16) * 1024 + kt + aseg,
                        smem + w * 2048 + t * 1024);
            gload_lds16(Bt + (size_t)(n0 + arow + t * 16) * 1024 + kt + aseg,
                        smem + 8192 + w * 2048 + t * 1024);
        }
        __syncthreads();
        bf16x8 af[4], bfv[4];
#pragma unroll
        for (int m = 0; m < 4; ++m)
            af[m] = *(const bf16x8*)(smem + (wr * 64 + m * 16 + fr) * 64 + fq * 16);
#pragma unroll
        for (int n = 0; n < 4; ++n)
            bfv[n] = *(const bf16x8*)(smem + 8192 + (wc * 64 + n * 16 + fr) * 64 + fq * 16);
#pragma unroll
        for (int m = 0; m < 4; ++m)
#pragma unroll
            for (int n = 0; n < 4; ++n)
                acc[m][n] = __builtin_amdgcn_mfma_f32_16x16x32_bf16(af[m], bfv[n], acc[m][n], 0, 0, 0);
        __syncthreads();
    }

#pragma unroll
    for (int m = 0; m < 4; ++m) {
#pragma unroll
        for (int n = 0; n < 4; ++n) {
            int col = n0 + wc * 64 + n * 16 + fr;
            float bvv = bias[col];
            int h = col >> 6, e = col & 63;
            if (mode == 0) {
#pragma unroll
                for (int j = 0; j < 4; ++j) {
                    int row = m0 + wr * 64 + m * 16 + fq * 4 + j;
                    int bb = row >> 11, s = row & 2047;
                    out[((size_t)(bb * 16 + h) * 2048 + s) * 64 + e] = f2bf(acc[m][n][j] + bvv);
                }
            } else {
                int row = m0 + wr * 64 + m * 16 + fq * 4;   // 4 consecutive s
                int bb = row >> 11, s = row & 2047;
                ushort4 o = make_ushort4(f2bf(acc[m][n][0] + bvv), f2bf(acc[m][n][1] + bvv),
                                         f2bf(acc[m][n][2] + bvv), f2bf(acc[m][n][3] + bvv));
                *(ushort4*)(out + ((size_t)(bb * 16 + h) * 64 + e) * 2048 + s) = o;
            }
        }
    }
}

// ---------------- flash attention ----------------
// Q,K: [B*H][2048][64] bf16; Vt: [B*H][64][2048] bf16; mbits: [B][2048][64] u32
// O: [B][2048][16*64] bf16
__global__ __launch_bounds__(256) void k_attn(
    const u16* __restrict__ Qg_, const u16* __restrict__ Kg_,
    const u16* __restrict__ Vg_, const u32* __restrict__ mbits,
    u16* __restrict__ O)
{
    __shared__ char smem[8192 * 2 + 16384];
    char* Ks = smem;
    char* Vs = smem + 8192;
    const int tid = threadIdx.x, lane = tid & 63, w = tid >> 6;
    const int fr = lane & 15, fq = lane >> 4;
    char* Ps = smem + 16384 + w * 4096;
    const int bh = blockIdx.y, b = bh >> 4, h = bh & 15;
    const int q0 = blockIdx.x * 128, wq0 = w * 32;

    const u16* Qg = Qg_ + (size_t)bh * 2048 * 64;
    const u16* Kg = Kg_ + (size_t)bh * 2048 * 64;
    const u16* Vg = Vg_ + (size_t)bh * 64 * 2048;

    // Q fragments in registers (reused across all KV tiles)
    bf16x8 qf[2][2];
#pragma unroll
    for (int m = 0; m < 2; ++m)
#pragma unroll
        for (int ks = 0; ks < 2; ++ks)
            qf[m][ks] = *(const bf16x8*)(Qg + (size_t)(q0 + wq0 + m * 16 + fr) * 64 + ks * 32 + fq * 8);

    f32x4 acc[2][4] = {};
    float mrow[2][4], lrow[2][4];
#pragma unroll
    for (int m = 0; m < 2; ++m)
#pragma unroll
        for (int j = 0; j < 4; ++j) { mrow[m][j] = -INFINITY; lrow[m][j] = 0.f; }

    const int srow = w * 16 + (lane >> 3);  // +t*8
    const int sseg0 = lane & 7;

    for (int kv0 = 0; kv0 < 2048; kv0 += 64) {
        // stage K [64 kv][64 e] and Vt [64 e][64 kv], XOR-swizzled via pre-swizzled source
#pragma unroll
        for (int t = 0; t < 2; ++t) {
            int row = srow + t * 8;
            int seg = sseg0 ^ (row & 7);
            gload_lds16(Kg + (size_t)(kv0 + row) * 64 + seg * 8, Ks + w * 2048 + t * 1024);
            gload_lds16(Vg + (size_t)row * 2048 + kv0 + seg * 8, Vs + w * 2048 + t * 1024);
        }
        __syncthreads();

        // QK^T : scores[q 32][kv 64] per wave
        f32x4 sc[2][4] = {};
#pragma unroll
        for (int ks = 0; ks < 2; ++ks) {
#pragma unroll
            for (int n = 0; n < 4; ++n) {
                int row = n * 16 + fr;
                int c16 = (ks * 4 + fq) ^ (row & 7);
                bf16x8 kf = *(const bf16x8*)(Ks + row * 128 + c16 * 16);
#pragma unroll
                for (int m = 0; m < 2; ++m)
                    sc[m][n] = __builtin_amdgcn_mfma_f32_16x16x32_bf16(qf[m][ks], kf, sc[m][n], 0, 0, 0);
            }
        }

        // mask + online softmax
        const int wword = kv0 >> 5;
#pragma unroll
        for (int m = 0; m < 2; ++m) {
#pragma unroll
            for (int j = 0; j < 4; ++j) {
                int qg = q0 + wq0 + m * 16 + fq * 4 + j;
                const u32* mbp = mbits + ((size_t)b * 2048 + qg) * 64 + wword;
                u32 w0 = mbp[0], w1 = mbp[1];
#pragma unroll
                for (int n = 0; n < 4; ++n) {
                    int kvl = n * 16 + fr;
                    u32 word = (n < 2) ? w0 : w1;
                    if (!((word >> (kvl & 31)) & 1)) sc[m][n][j] = -1e9f;
                }
                float tmax = fmaxf(fmaxf(sc[m][0][j], sc[m][1][j]), fmaxf(sc[m][2][j], sc[m][3][j]));
#pragma unroll
                for (int d = 1; d < 16; d <<= 1) tmax = fmaxf(tmax, __shfl_xor(tmax, d, 64));
                float mo = mrow[m][j];
                float mn = fmaxf(mo, tmax);
                float scale = __expf(mo - mn);
                float rs = 0.f;
#pragma unroll
                for (int n = 0; n < 4; ++n) {
                    float p = __expf(sc[m][n][j] - mn);
                    sc[m][n][j] = p;
                    rs += p;
                }
#pragma unroll
                for (int d = 1; d < 16; d <<= 1) rs += __shfl_xor(rs, d, 64);
                lrow[m][j] = lrow[m][j] * scale + rs;
                mrow[m][j] = mn;
#pragma unroll
                for (int ne = 0; ne < 4; ++ne) acc[m][ne][j] *= scale;
            }
        }

        // P -> per-wave LDS (swizzled), then PV
#pragma unroll
        for (int m = 0; m < 2; ++m)
#pragma unroll
            for (int n = 0; n < 4; ++n)
#pragma unroll
                for (int j = 0; j < 4; ++j) {
                    int ql = m * 16 + fq * 4 + j;
                    int kvl = n * 16 + fr;
                    *(u16*)(Ps + ql * 128 + (((kvl >> 3) ^ (ql & 7)) << 4) + (kvl & 7) * 2) =
                        f2bf(sc[m][n][j]);
                }

#pragma unroll
        for (int ks = 0; ks < 2; ++ks) {
            bf16x8 pf[2];
#pragma unroll
            for (int m = 0; m < 2; ++m) {
                int row = m * 16 + fr;
                pf[m] = *(const bf16x8*)(Ps + row * 128 + (((ks * 4 + fq) ^ (row & 7)) << 4));
            }
#pragma unroll
            for (int ne = 0; ne < 4; ++ne) {
                int vrow = ne * 16 + fr;
                int c16 = (ks * 4 + fq) ^ (vrow & 7);
                bf16x8 vf = *(const bf16x8*)(Vs + vrow * 128 + c16 * 16);
#pragma unroll
                for (int m = 0; m < 2; ++m)
                    acc[m][ne] = __builtin_amdgcn_mfma_f32_16x16x32_bf16(pf[m], vf, acc[m][ne], 0, 0, 0);
            }
        }
        __syncthreads();
    }

    // epilogue: O[b][sq][h*64 + e]
#pragma unroll
    for (int m = 0; m < 2; ++m)
#pragma unroll
        for (int j = 0; j < 4; ++j) {
            float inv = 1.0f / lrow[m][j];
            int sq = q0 + wq0 + m * 16 + fq * 4 + j;
#pragma unroll
            for (int ne = 0; ne < 4; ++ne)
                O[((size_t)b * 2048 + sq) * 1024 + h * 64 + ne * 16 + fr] =
                    f2bf(acc[m][ne][j] * inv);
        }
}

// ---------------- output projection: [8192,1024] @ [1024,64] + bo -> f32 ----------------
__global__ __launch_bounds__(256) void k_oproj(
    const u16* __restrict__ A, const u16* __restrict__ Bt,
    const float* __restrict__ bo, float* __restrict__ out)
{
    __shared__ char smem[8192 + 4096];
    const int tid = threadIdx.x, lane = tid & 63, w = tid >> 6;
    const int fr = lane & 15, fq = lane >> 4;
    const int m0 = blockIdx.x * 128;

    const int arow = w * 32 + (lane >> 2);
    const int aseg = (lane & 3) * 8;
    const int brow = w * 16 + (lane >> 2);

    f32x4 acc[2][4] = {};

    for (int kt = 0; kt < 1024; kt += 32) {
#pragma unroll
        for (int t = 0; t < 2; ++t)
            gload_lds16(A + (size_t)(m0 + arow + t * 16) * 1024 + kt + aseg,
                        smem + w * 2048 + t * 1024);
        gload_lds16(Bt + (size_t)brow * 1024 + kt + aseg, smem + 8192 + w * 1024);
        __syncthreads();
        bf16x8 af[2], bfv[4];
#pragma unroll
        for (int m = 0; m < 2; ++m)
            af[m] = *(const bf16x8*)(smem + (w * 32 + m * 16 + fr) * 64 + fq * 16);
#pragma unroll
        for (int n = 0; n < 4; ++n)
            bfv[n] = *(const bf16x8*)(smem + 8192 + (n * 16 + fr) * 64 + fq * 16);
#pragma unroll
        for (int m = 0; m < 2; ++m)
#pragma unroll
            for (int n = 0; n < 4; ++n)
                acc[m][n] = __builtin_amdgcn_mfma_f32_16x16x32_bf16(af[m], bfv[n], acc[m][n], 0, 0, 0);
        __syncthreads();
    }

#pragma unroll
    for (int m = 0; m < 2; ++m)
#pragma unroll
        for (int n = 0; n < 4; ++n) {
            float bb = bo[n * 16 + fr];
#pragma unroll
            for (int j = 0; j < 4; ++j)
                out[(size_t)(m0 + w * 32 + m * 16 + fq * 4 + j) * 64 + n * 16 + fr] =
                    acc[m][n][j] + bb;
        }
}

extern "C" void kernel_launch(void* const* d_in, const int* in_sizes, int n_in,
                              void* d_out, int out_size, void* d_ws, size_t ws_size,
                              hipStream_t stream) {
    const float* query = (const float*)d_in[0];
    const float* key   = (const float*)d_in[1];
    const float* value = (const float*)d_in[2];
    const int*   mask  = (const int*)d_in[3];
    const float* Wq = (const float*)d_in[4];
    const float* bq = (const float*)d_in[5];
    const float* Wk = (const float*)d_in[6];
    const float* bk = (const float*)d_in[7];
    const float* Wv = (const float*)d_in[8];
    const float* bv = (const float*)d_in[9];
    const float* Wo = (const float*)d_in[10];
    const float* bo = (const float*)d_in[11];
    float* out = (float*)d_out;

    char* ws = (char*)d_ws;
    size_t off = 0;
    auto alloc = [&](size_t bytes) {
        size_t o = off;
        off += (bytes + 255) & ~(size_t)255;
        return o;
    };
    u16* xq  = (u16*)(ws + alloc(16777216));
    u16* xk  = (u16*)(ws + alloc(16777216));
    u16* xv  = (u16*)(ws + alloc(16777216));
    u16* wtq = (u16*)(ws + alloc(2097152));
    u16* wtk = (u16*)(ws + alloc(2097152));
    u16* wtv = (u16*)(ws + alloc(2097152));
    u16* wot = (u16*)(ws + alloc(131072));
    u16* qh  = (u16*)(ws + alloc(16777216));
    u16* kh  = (u16*)(ws + alloc(16777216));
    u16* vt  = (u16*)(ws + alloc(16777216));
    u32* mb  = (u32*)(ws + alloc(2097152));
    u16* attno = xq;  // alias: xq is dead after the q-projection

    k_cvt<<<2048, 256, 0, stream>>>(query, xq, 8388608);
    k_cvt<<<2048, 256, 0, stream>>>(key,   xk, 8388608);
    k_cvt<<<2048, 256, 0, stream>>>(value, xv, 8388608);
    k_pack_w<<<4096, 256, 0, stream>>>(Wq, wtq);
    k_pack_w<<<4096, 256, 0, stream>>>(Wk, wtk);
    k_pack_w<<<4096, 256, 0, stream>>>(Wv, wtv);
    k_pack_wo<<<256, 256, 0, stream>>>(Wo, wot);
    k_pack_mask<<<65536, 256, 0, stream>>>(mask, mb);

    k_proj<<<dim3(8, 64), 256, 0, stream>>>(xq, wtq, bq, qh, 0);
    k_proj<<<dim3(8, 64), 256, 0, stream>>>(xk, wtk, bk, kh, 0);
    k_proj<<<dim3(8, 64), 256, 0, stream>>>(xv, wtv, bv, vt, 1);

    k_attn<<<dim3(16, 64), 256, 0, stream>>>(qh, kh, vt, mb, attno);

    k_oproj<<<64, 256, 0, stream>>>(attno, wot, bo, out);
}

// Round 2
// 324.371 us; speedup vs baseline: 1.3854x; 1.3854x over previous
//
#include <hip/hip_runtime.h>
#include <hip/hip_bf16.h>

typedef __attribute__((ext_vector_type(8))) short bf16x8;
typedef __attribute__((ext_vector_type(4))) float f32x4;
typedef unsigned int u32;
typedef unsigned short u16;
typedef unsigned long long u64;

// B=4, S=2048, D=1024, H=16, DH=64

__device__ __forceinline__ void gload_lds16(const void* g, void* l) {
    __builtin_amdgcn_global_load_lds(
        (const __attribute__((address_space(1))) void*)g,
        (__attribute__((address_space(3))) void*)l, 16, 0, 0);
}

__device__ __forceinline__ u16 f2bf(float f) {
    u32 u = __builtin_bit_cast(u32, f);
    u32 r = u + 0x7fffu + ((u >> 16) & 1u);
    return (u16)(r >> 16);
}

// ---------------- f32 -> bf16 convert (vectorized, grid-stride) ----------------
__global__ void k_cvt(const float* __restrict__ in, u16* __restrict__ out, int n) {
    int i = (blockIdx.x * blockDim.x + threadIdx.x) * 4;
    int stride = gridDim.x * blockDim.x * 4;
    for (; i < n; i += stride) {
        float4 v = *(const float4*)(in + i);
        ushort4 o = make_ushort4(f2bf(v.x), f2bf(v.y), f2bf(v.z), f2bf(v.w));
        *(ushort4*)(out + i) = o;
    }
}

// ---------------- pack [H][D][DH] f32 -> bf16 Bt [H*DH][D] ----------------
__global__ void k_pack_w(const float* __restrict__ W, u16* __restrict__ Wt) {
    int i = blockIdx.x * 256 + threadIdx.x;   // over 16*1024*64 = 1048576
    int h = i >> 16;
    int r = i & 65535;
    int k = r >> 6, e = r & 63;
    Wt[(size_t)(h * 64 + e) * 1024 + k] = f2bf(W[i]);
}

// ---------------- pack Wo [1024][64] -> bf16 [64][1024] ----------------
__global__ void k_pack_wo(const float* __restrict__ W, u16* __restrict__ Wt) {
    int i = blockIdx.x * 256 + threadIdx.x;   // over 65536
    int k = i >> 6, e = i & 63;
    Wt[(size_t)e * 1024 + k] = f2bf(W[i]);
}

// ---------------- pack mask int32 -> bitmask ----------------
__global__ void k_pack_mask(const int* __restrict__ mask, u32* __restrict__ bits) {
    size_t i = (size_t)blockIdx.x * 256 + threadIdx.x;  // over B*S*S = 16777216
    int m = mask[i];
    u64 bal = __ballot(m != 0);
    if ((threadIdx.x & 63) == 0) *(u64*)(bits + (i >> 5)) = bal;
}

// ---------------- projection GEMM: C[8192,1024] = A[8192,1024] @ Bt^T + bias ----------------
// mode 0: out[((b*16+h)*2048 + s)*64 + e]   (q, k)
// mode 1: out[((b*16+h)*64 + e)*2048 + s]   (v transposed)
// oscale: extra scalar applied to (acc + bias) -- used to fold log2(e) into q
__global__ __launch_bounds__(256) void k_proj(
    const u16* __restrict__ A, const u16* __restrict__ Bt,
    const float* __restrict__ bias, u16* __restrict__ out, int mode, float oscale)
{
    __shared__ char smem[16384];
    const int tid = threadIdx.x, lane = tid & 63, w = tid >> 6;
    const int wr = w >> 1, wc = w & 1;
    const int fr = lane & 15, fq = lane >> 4;

    // XCD-aware remap: each XCD owns a contiguous band of 8 row-blocks so the
    // A band (2 MB) + full B (2 MB) stay L2-resident per XCD.
    const int flat = blockIdx.y * 8 + blockIdx.x;     // 0..511
    const int xcd = flat & 7, idx = flat >> 3;        // idx 0..63
    const int xb = idx >> 3;                          // 0..7  (col block)
    const int yb = xcd * 8 + (idx & 7);               // 0..63 (row block)
    const int m0 = yb * 128, n0 = xb * 128;

    const int arow = w * 32 + (lane >> 2);   // +t*16
    const int aseg = (lane & 3) * 8;

    f32x4 acc[4][4] = {};

    for (int kt = 0; kt < 1024; kt += 32) {
#pragma unroll
        for (int t = 0; t < 2; ++t) {
            gload_lds16(A + (size_t)(m0 + arow + t * 16) * 1024 + kt + aseg,
                        smem + w * 2048 + t * 1024);
            gload_lds16(Bt + (size_t)(n0 + arow + t * 16) * 1024 + kt + aseg,
                        smem + 8192 + w * 2048 + t * 1024);
        }
        __syncthreads();
        bf16x8 af[4], bfv[4];
#pragma unroll
        for (int m = 0; m < 4; ++m)
            af[m] = *(const bf16x8*)(smem + (wr * 64 + m * 16 + fr) * 64 + fq * 16);
#pragma unroll
        for (int n = 0; n < 4; ++n)
            bfv[n] = *(const bf16x8*)(smem + 8192 + (wc * 64 + n * 16 + fr) * 64 + fq * 16);
#pragma unroll
        for (int m = 0; m < 4; ++m)
#pragma unroll
            for (int n = 0; n < 4; ++n)
                acc[m][n] = __builtin_amdgcn_mfma_f32_16x16x32_bf16(af[m], bfv[n], acc[m][n], 0, 0, 0);
        __syncthreads();
    }

#pragma unroll
    for (int m = 0; m < 4; ++m) {
#pragma unroll
        for (int n = 0; n < 4; ++n) {
            int col = n0 + wc * 64 + n * 16 + fr;
            float bvv = bias[col];
            int h = col >> 6, e = col & 63;
            if (mode == 0) {
#pragma unroll
                for (int j = 0; j < 4; ++j) {
                    int row = m0 + wr * 64 + m * 16 + fq * 4 + j;
                    int bb = row >> 11, s = row & 2047;
                    out[((size_t)(bb * 16 + h) * 2048 + s) * 64 + e] = f2bf((acc[m][n][j] + bvv) * oscale);
                }
            } else {
                int row = m0 + wr * 64 + m * 16 + fq * 4;   // 4 consecutive s
                int bb = row >> 11, s = row & 2047;
                ushort4 o = make_ushort4(f2bf(acc[m][n][0] + bvv), f2bf(acc[m][n][1] + bvv),
                                         f2bf(acc[m][n][2] + bvv), f2bf(acc[m][n][3] + bvv));
                *(ushort4*)(out + ((size_t)(bb * 16 + h) * 64 + e) * 2048 + s) = o;
            }
        }
    }
}

// ---------------- flash attention (no-max softmax, double-buffered K/V) ----------------
// Q (pre-scaled by log2e), K: [B*H][2048][64] bf16; Vt: [B*H][64][2048] bf16
// mbits: [B][2048][64] u32;  O: [B][2048][16*64] bf16
__global__ __launch_bounds__(256) void k_attn(
    const u16* __restrict__ Qg_, const u16* __restrict__ Kg_,
    const u16* __restrict__ Vg_, const u32* __restrict__ mbits,
    u16* __restrict__ O)
{
    // double-buffered K/V: 2 x (K 8KB + V 8KB) = 32KB, + per-wave P 16KB
    __shared__ char smem[49152];
    const int tid = threadIdx.x, lane = tid & 63, w = tid >> 6;
    const int fr = lane & 15, fq = lane >> 4;
    char* Ps = smem + 32768 + w * 4096;

    // XCD swizzle: flat grid 1024 = 64 bh x 16 qtiles; give each XCD 8 whole
    // heads so K/V (512KB/head) stay L2-resident.
    const int bid = blockIdx.x;
    const int wg = (bid & 7) * 128 + (bid >> 3);
    const int bh = wg >> 4, qt = wg & 15;
    const int b = bh >> 4;
    const int q0 = qt * 128, wq0 = w * 32;

    const u16* Qg = Qg_ + (size_t)bh * 2048 * 64;
    const u16* Kg = Kg_ + (size_t)bh * 2048 * 64;
    const u16* Vg = Vg_ + (size_t)bh * 64 * 2048;

    // Q fragments in registers (reused across all KV tiles)
    bf16x8 qf[2][2];
#pragma unroll
    for (int m = 0; m < 2; ++m)
#pragma unroll
        for (int ks = 0; ks < 2; ++ks)
            qf[m][ks] = *(const bf16x8*)(Qg + (size_t)(q0 + wq0 + m * 16 + fr) * 64 + ks * 32 + fq * 8);

    f32x4 acc[2][4] = {};
    f32x4 acc_l[2] = {};   // row sums via ones-column MFMA

    const bf16x8 onesv = {(short)0x3F80, (short)0x3F80, (short)0x3F80, (short)0x3F80,
                          (short)0x3F80, (short)0x3F80, (short)0x3F80, (short)0x3F80};

    const int srow = w * 16 + (lane >> 3);  // +tt*8
    const int sseg0 = lane & 7;

    // stage tile 0 into buffer 0
#pragma unroll
    for (int tt = 0; tt < 2; ++tt) {
        int row = srow + tt * 8;
        int seg = sseg0 ^ (row & 7);
        gload_lds16(Kg + (size_t)row * 64 + seg * 8, smem + w * 2048 + tt * 1024);
        gload_lds16(Vg + (size_t)row * 2048 + seg * 8, smem + 8192 + w * 2048 + tt * 1024);
    }
    __syncthreads();

    const u32* mrow_base = mbits + ((size_t)b * 2048 + q0 + wq0) * 64;

    for (int t = 0; t < 32; ++t) {
        const int cur = t & 1;
        char* Ks = smem + cur * 16384;
        char* Vs = Ks + 8192;

        // prefetch next tile into the other buffer (overlaps all compute below)
        if (t + 1 < 32) {
            char* Kn = smem + (cur ^ 1) * 16384;
            int kvn = (t + 1) * 64;
#pragma unroll
            for (int tt = 0; tt < 2; ++tt) {
                int row = srow + tt * 8;
                int seg = sseg0 ^ (row & 7);
                gload_lds16(Kg + (size_t)(kvn + row) * 64 + seg * 8, Kn + w * 2048 + tt * 1024);
                gload_lds16(Vg + (size_t)row * 2048 + kvn + seg * 8, Kn + 8192 + w * 2048 + tt * 1024);
            }
        }

        // mask words for this tile (8 rows per lane)
        u64 mw[2][4];
#pragma unroll
        for (int m = 0; m < 2; ++m)
#pragma unroll
            for (int j = 0; j < 4; ++j)
                mw[m][j] = *(const u64*)(mrow_base + (size_t)(m * 16 + fq * 4 + j) * 64 + t * 2);

        // QK^T : scores[q 32][kv 64] per wave (already in log2 units via Q prescale)
        f32x4 sc[2][4] = {};
#pragma unroll
        for (int ks = 0; ks < 2; ++ks) {
#pragma unroll
            for (int n = 0; n < 4; ++n) {
                int row = n * 16 + fr;
                int c16 = (ks * 4 + fq) ^ (row & 7);
                bf16x8 kf = *(const bf16x8*)(Ks + row * 128 + c16 * 16);
#pragma unroll
                for (int m = 0; m < 2; ++m)
                    sc[m][n] = __builtin_amdgcn_mfma_f32_16x16x32_bf16(qf[m][ks], kf, sc[m][n], 0, 0, 0);
            }
        }

        // mask + exp2 + P -> per-wave LDS (swizzled). No max, no rescale.
#pragma unroll
        for (int m = 0; m < 2; ++m) {
#pragma unroll
            for (int j = 0; j < 4; ++j) {
                u32 lo = (u32)mw[m][j], hi = (u32)(mw[m][j] >> 32);
                int ql = m * 16 + fq * 4 + j;
#pragma unroll
                for (int n = 0; n < 4; ++n) {
                    u32 word = (n < 2) ? lo : hi;
                    u32 bit = (word >> (((n & 1) << 4) + fr)) & 1u;
                    float e = __builtin_amdgcn_exp2f(sc[m][n][j]);
                    float p = bit ? e : 0.f;
                    int kvl = n * 16 + fr;
                    *(u16*)(Ps + ql * 128 + (((kvl >> 3) ^ (ql & 7)) << 4) + (kvl & 7) * 2) = f2bf(p);
                }
            }
        }

        // PV + rowsum (ones column)
#pragma unroll
        for (int ks = 0; ks < 2; ++ks) {
            bf16x8 pf[2];
#pragma unroll
            for (int m = 0; m < 2; ++m) {
                int row = m * 16 + fr;
                pf[m] = *(const bf16x8*)(Ps + row * 128 + (((ks * 4 + fq) ^ (row & 7)) << 4));
            }
#pragma unroll
            for (int m = 0; m < 2; ++m)
                acc_l[m] = __builtin_amdgcn_mfma_f32_16x16x32_bf16(pf[m], onesv, acc_l[m], 0, 0, 0);
#pragma unroll
            for (int ne = 0; ne < 4; ++ne) {
                int vrow = ne * 16 + fr;
                int c16 = (ks * 4 + fq) ^ (vrow & 7);
                bf16x8 vf = *(const bf16x8*)(Vs + vrow * 128 + c16 * 16);
#pragma unroll
                for (int m = 0; m < 2; ++m)
                    acc[m][ne] = __builtin_amdgcn_mfma_f32_16x16x32_bf16(pf[m], vf, acc[m][ne], 0, 0, 0);
            }
        }
        __syncthreads();
    }

    // epilogue: O[b][sq][h*64 + e]
    const int h = bh & 15;
#pragma unroll
    for (int m = 0; m < 2; ++m)
#pragma unroll
        for (int j = 0; j < 4; ++j) {
            float inv = 1.0f / acc_l[m][j];
            int sq = q0 + wq0 + m * 16 + fq * 4 + j;
#pragma unroll
            for (int ne = 0; ne < 4; ++ne)
                O[((size_t)b * 2048 + sq) * 1024 + h * 64 + ne * 16 + fr] =
                    f2bf(acc[m][ne][j] * inv);
        }
}

// ---------------- output projection: [8192,1024] @ [1024,64] + bo -> f32 ----------------
__global__ __launch_bounds__(256) void k_oproj(
    const u16* __restrict__ A, const u16* __restrict__ Bt,
    const float* __restrict__ bo, float* __restrict__ out)
{
    __shared__ char smem[8192 + 4096];
    const int tid = threadIdx.x, lane = tid & 63, w = tid >> 6;
    const int fr = lane & 15, fq = lane >> 4;
    const int m0 = blockIdx.x * 128;

    const int arow = w * 32 + (lane >> 2);
    const int aseg = (lane & 3) * 8;
    const int brow = w * 16 + (lane >> 2);

    f32x4 acc[2][4] = {};

    for (int kt = 0; kt < 1024; kt += 32) {
#pragma unroll
        for (int t = 0; t < 2; ++t)
            gload_lds16(A + (size_t)(m0 + arow + t * 16) * 1024 + kt + aseg,
                        smem + w * 2048 + t * 1024);
        gload_lds16(Bt + (size_t)brow * 1024 + kt + aseg, smem + 8192 + w * 1024);
        __syncthreads();
        bf16x8 af[2], bfv[4];
#pragma unroll
        for (int m = 0; m < 2; ++m)
            af[m] = *(const bf16x8*)(smem + (w * 32 + m * 16 + fr) * 64 + fq * 16);
#pragma unroll
        for (int n = 0; n < 4; ++n)
            bfv[n] = *(const bf16x8*)(smem + 8192 + (n * 16 + fr) * 64 + fq * 16);
#pragma unroll
        for (int m = 0; m < 2; ++m)
#pragma unroll
            for (int n = 0; n < 4; ++n)
                acc[m][n] = __builtin_amdgcn_mfma_f32_16x16x32_bf16(af[m], bfv[n], acc[m][n], 0, 0, 0);
        __syncthreads();
    }

#pragma unroll
    for (int m = 0; m < 2; ++m)
#pragma unroll
        for (int n = 0; n < 4; ++n) {
            float bb = bo[n * 16 + fr];
#pragma unroll
            for (int j = 0; j < 4; ++j)
                out[(size_t)(m0 + w * 32 + m * 16 + fq * 4 + j) * 64 + n * 16 + fr] =
                    acc[m][n][j] + bb;
        }
}

extern "C" void kernel_launch(void* const* d_in, const int* in_sizes, int n_in,
                              void* d_out, int out_size, void* d_ws, size_t ws_size,
                              hipStream_t stream) {
    const float* query = (const float*)d_in[0];
    const float* key   = (const float*)d_in[1];
    const float* value = (const float*)d_in[2];
    const int*   mask  = (const int*)d_in[3];
    const float* Wq = (const float*)d_in[4];
    const float* bq = (const float*)d_in[5];
    const float* Wk = (const float*)d_in[6];
    const float* bk = (const float*)d_in[7];
    const float* Wv = (const float*)d_in[8];
    const float* bv = (const float*)d_in[9];
    const float* Wo = (const float*)d_in[10];
    const float* bo = (const float*)d_in[11];
    float* out = (float*)d_out;

    char* ws = (char*)d_ws;
    size_t off = 0;
    auto alloc = [&](size_t bytes) {
        size_t o = off;
        off += (bytes + 255) & ~(size_t)255;
        return o;
    };
    u16* xq  = (u16*)(ws + alloc(16777216));
    u16* xk  = (u16*)(ws + alloc(16777216));
    u16* xv  = (u16*)(ws + alloc(16777216));
    u16* wtq = (u16*)(ws + alloc(2097152));
    u16* wtk = (u16*)(ws + alloc(2097152));
    u16* wtv = (u16*)(ws + alloc(2097152));
    u16* wot = (u16*)(ws + alloc(131072));
    u16* qh  = (u16*)(ws + alloc(16777216));
    u16* kh  = (u16*)(ws + alloc(16777216));
    u16* vt  = (u16*)(ws + alloc(16777216));
    u32* mb  = (u32*)(ws + alloc(2097152));
    u16* attno = xq;  // alias: xq is dead after the q-projection

    k_cvt<<<2048, 256, 0, stream>>>(query, xq, 8388608);
    k_cvt<<<2048, 256, 0, stream>>>(key,   xk, 8388608);
    k_cvt<<<2048, 256, 0, stream>>>(value, xv, 8388608);
    k_pack_w<<<4096, 256, 0, stream>>>(Wq, wtq);
    k_pack_w<<<4096, 256, 0, stream>>>(Wk, wtk);
    k_pack_w<<<4096, 256, 0, stream>>>(Wv, wtv);
    k_pack_wo<<<256, 256, 0, stream>>>(Wo, wot);
    k_pack_mask<<<65536, 256, 0, stream>>>(mask, mb);

    // fold log2(e) into q so attention can use raw v_exp_f32 (exp2)
    k_proj<<<dim3(8, 64), 256, 0, stream>>>(xq, wtq, bq, qh, 0, 1.44269504088896f);
    k_proj<<<dim3(8, 64), 256, 0, stream>>>(xk, wtk, bk, kh, 0, 1.0f);
    k_proj<<<dim3(8, 64), 256, 0, stream>>>(xv, wtv, bv, vt, 1, 1.0f);

    k_attn<<<1024, 256, 0, stream>>>(qh, kh, vt, mb, attno);

    k_oproj<<<64, 256, 0, stream>>>(attno, wot, bo, out);
}